// Round 10
// baseline (88.670 us; speedup 1.0000x reference)
//
#include <hip/hip_runtime.h>
#include <hip/hip_bf16.h>
#include <stdint.h>

#define BB   16
#define JJ   256
#define KK   384
#define NROW (BB * JJ)               // 4096
#define NPOS ((size_t)BB * JJ * KK)  // 1572864

// ws layout (bytes)
#define WS_FLAG  0
#define WS_SEL   64                          // int[16*32]
#define WS_VINT  2176                        // int[4096]
#define WS_VBYTE (WS_VINT + NROW * 4)        // int[4096]
#define WS_PART  (WS_VBYTE + NROW * 4)       // float[512][33]
#define WS_REPB  (WS_PART + 512 * 33 * 4)    // float[16][32]

typedef float f32x4 __attribute__((ext_vector_type(4)));
typedef short bf16x8 __attribute__((ext_vector_type(8)));

struct FragU { union { bf16x8 v; uint32_t u[4]; }; };

__device__ __forceinline__ uint32_t rotl32(uint32_t x, int r) {
  return (x << r) | (x >> (32 - r));
}

__device__ __forceinline__ void threefry2x32_k42(uint32_t c0, uint32_t c1,
                                                 uint32_t& o0, uint32_t& o1) {
  const uint32_t ks0 = 0u, ks1 = 42u, ks2 = 0x1BD11BDAu ^ 0u ^ 42u;
  uint32_t x0 = c0 + ks0, x1 = c1 + ks1;
#define TFR(r) { x0 += x1; x1 = rotl32(x1, r); x1 ^= x0; }
  TFR(13) TFR(15) TFR(26) TFR(6)   x0 += ks1; x1 += ks2 + 1u;
  TFR(17) TFR(29) TFR(16) TFR(24)  x0 += ks2; x1 += ks0 + 2u;
  TFR(13) TFR(15) TFR(26) TFR(6)   x0 += ks0; x1 += ks1 + 3u;
  TFR(17) TFR(29) TFR(16) TFR(24)  x0 += ks1; x1 += ks2 + 4u;
  TFR(13) TFR(15) TFR(26) TFR(6)   x0 += ks2; x1 += ks0 + 5u;
#undef TFR
  o0 = x0; o1 = x1;
}

__device__ __forceinline__ uint32_t jax_bits(uint32_t t) {
  uint32_t o0, o1;
  threefry2x32_k42(0u, t, o0, o1);
  return o0 ^ o1;
}

// split f32 -> hi/lo bf16 (RNE), x ~= hi + lo
__device__ __forceinline__ void split2(float x, short& h, short& l) {
  const unsigned short hu = __builtin_bit_cast(unsigned short, __float2bfloat16(x));
  const float hf = __builtin_bit_cast(float, (uint32_t)hu << 16);
  h = (short)hu;
  l = (short)__builtin_bit_cast(unsigned short, __float2bfloat16(x - hf));
}

// split a pair -> packed hi-pair and lo-pair
__device__ __forceinline__ void split_pk(float x0, float x1,
                                         uint32_t& ph, uint32_t& pl) {
  const uint32_t h0 = (uint32_t)__builtin_bit_cast(unsigned short, __float2bfloat16(x0));
  const uint32_t h1 = (uint32_t)__builtin_bit_cast(unsigned short, __float2bfloat16(x1));
  ph = h0 | (h1 << 16);
  const float f0 = __builtin_bit_cast(float, h0 << 16);
  const float f1 = __builtin_bit_cast(float, h1 << 16);
  const uint32_t l0 = (uint32_t)__builtin_bit_cast(unsigned short, __float2bfloat16(x0 - f0));
  const uint32_t l1 = (uint32_t)__builtin_bit_cast(unsigned short, __float2bfloat16(x1 - f1));
  pl = l0 | (l1 << 16);
}

// --- 1. row validity under BOTH mask-width interpretations ---
__global__ __launch_bounds__(256) void k_valid(const void* __restrict__ maskp,
                                               int* __restrict__ valid_int,
                                               int* __restrict__ valid_byte) {
  const int row = blockIdx.x * 4 + (threadIdx.x >> 6);
  const int lane = threadIdx.x & 63;
  const uint32_t* wi = (const uint32_t*)maskp + (size_t)row * 384;
  int v = 0;
#pragma unroll
  for (int i = 0; i < 6; ++i) v |= (wi[lane + i * 64] != 0u);
  const unsigned long long bi = __ballot(v);
  const uint32_t* wb = (const uint32_t*)maskp + (size_t)row * 96;
  int u = 0;
  for (int i = lane; i < 96; i += 64) u |= (wb[i] != 0u);
  const unsigned long long bu = __ballot(u);
  if (lane == 0) {
    valid_int[row] = (bi != 0ull) ? 1 : 0;
    valid_byte[row] = (bu != 0ull) ? 1 : 0;
  }
}

// --- 2. detect mask width + per-batch top-S gumbel selection ---
__global__ void k_select(const void* __restrict__ maskp,
                         const int* __restrict__ valid_int,
                         const int* __restrict__ valid_byte,
                         const int* __restrict__ sample_size,
                         int* __restrict__ flag_out, int* __restrict__ sel) {
  const int b = blockIdx.x, lane = threadIdx.x;  // 16 x 64
  const uint32_t* mw = (const uint32_t*)maskp;
  int big = 0;
#pragma unroll
  for (int i = 0; i < 16; ++i) big |= (mw[lane + i * 64] > 1u);
  const int fl = (__ballot(big) != 0ull) ? 1 : 0;
  if (b == 0 && lane == 0) flag_out[0] = fl;
  const int* valid = fl ? valid_byte : valid_int;

  uint32_t comp[4];
#pragma unroll
  for (int q = 0; q < 4; ++q) {
    const int j = lane * 4 + q;
    const uint32_t ub = jax_bits((uint32_t)(b * 256 + j)) >> 9;
    const uint32_t key = valid[b * 256 + j] ? (ub + 1u) : 0u;
    comp[q] = (key << 8) | (uint32_t)(255 - j);  // tie -> smaller j wins
  }
  int S = sample_size[0];
  if (S > 32) S = 32;
  for (int s = 0; s < S; ++s) {
    uint32_t wm = comp[0];
    wm = comp[1] > wm ? comp[1] : wm;
    wm = comp[2] > wm ? comp[2] : wm;
    wm = comp[3] > wm ? comp[3] : wm;
#pragma unroll
    for (int off = 32; off; off >>= 1) {
      const uint32_t o = __shfl_xor(wm, off);
      wm = o > wm ? o : wm;
    }
    if (wm == 0u) {
      if (lane == 0) sel[b * 32 + s] = 0;
    } else {
#pragma unroll
      for (int q = 0; q < 4; ++q) {
        if (comp[q] == wm) {
          sel[b * 32 + s] = 255 - (int)(comp[q] & 0xFFu);
          comp[q] = 0u;
        }
      }
    }
  }
  for (int s2 = S + lane; s2 < 32; s2 += 64) sel[b * 32 + s2] = 0;
}

// --- 3. image branch via split-bf16 MFMA (proven R5-era version) ---
__global__ __launch_bounds__(256, 1) void k_image(
    const float* __restrict__ Imodel, const float* __restrict__ Iobs,
    const float* __restrict__ md, const void* __restrict__ maskp,
    const int* __restrict__ flag, const int* __restrict__ sel,
    const int* __restrict__ sample_size,
    const float* __restrict__ W_in, const float* __restrict__ b_in,
    const float* __restrict__ Wd, const float* __restrict__ bd,
    float* __restrict__ partial) {
  __shared__ float lds_t[4][16 * 36];
  __shared__ float red[4 * 33];
  const int tid = threadIdx.x, wid = tid >> 6, lane = tid & 63;
  const int g = lane >> 4, c = lane & 15;
  const int blk = blockIdx.x;   // 512 = b*32 + s
  const int b = blk >> 5, s = blk & 31;
  const bool active = (s < sample_size[0]);
  const int j = sel[b * 32 + s] & 255;
  const size_t pos0 = ((size_t)(b * JJ + j)) * KK + (size_t)wid * 96;
  const int fl = flag[0];

  float Win[8][8];
#pragma unroll
  for (int cc = 0; cc < 8; ++cc)
#pragma unroll
    for (int e = 0; e < 8; ++e) Win[cc][e] = W_in[cc * 32 + g * 8 + e];
  float b0v[8];
#pragma unroll
  for (int e = 0; e < 8; ++e) b0v[e] = b_in[g * 8 + e];

  bf16x8 Bh[3][2], Bl[3][2];
#pragma unroll
  for (int d = 0; d < 3; ++d)
#pragma unroll
    for (int ct = 0; ct < 2; ++ct)
#pragma unroll
      for (int e = 0; e < 8; ++e) {
        const float w = Wd[d * 1024 + (g * 8 + e) * 32 + ct * 16 + c];
        short hh, ll; split2(w, hh, ll);
        Bh[d][ct][e] = hh; Bl[d][ct][e] = ll;
      }
  float bias_v[3][2];
#pragma unroll
  for (int d = 0; d < 3; ++d) {
    bias_v[d][0] = bd[d * 32 + c];
    bias_v[d][1] = bd[d * 32 + 16 + c];
  }
  float* myl = lds_t[wid];

  float acc0 = 0.f, acc1 = 0.f, cntv = 0.f;

  for (int t = 0; t < 6; ++t) {
    const size_t tb = pos0 + (size_t)t * 16;
    const size_t p = tb + c;
    float in[8];
    in[0] = Imodel[p];
    in[1] = Iobs[p];
    const float* mp = md + p * 6;
    const float2 v0 = *(const float2*)(mp);
    const float2 v1 = *(const float2*)(mp + 2);
    const float2 v2 = *(const float2*)(mp + 4);
    in[2] = v0.x; in[3] = v0.y; in[4] = v1.x; in[5] = v1.y;
    in[6] = v2.x; in[7] = v2.y;

    bf16x8 ah, al;
#pragma unroll
    for (int e = 0; e < 8; ++e) {
      float h = b0v[e];
#pragma unroll
      for (int cc = 0; cc < 8; ++cc) h = fmaf(in[cc], Win[cc][e], h);
      short hh, ll; split2(h, hh, ll);
      ah[e] = hh; al[e] = ll;
    }

#pragma unroll
    for (int d = 0; d < 3; ++d) {
      f32x4 a0 = {0.f, 0.f, 0.f, 0.f}, a1 = {0.f, 0.f, 0.f, 0.f};
      a0 = __builtin_amdgcn_mfma_f32_16x16x32_bf16(ah, Bh[d][0], a0, 0, 0, 0);
      a0 = __builtin_amdgcn_mfma_f32_16x16x32_bf16(al, Bh[d][0], a0, 0, 0, 0);
      a0 = __builtin_amdgcn_mfma_f32_16x16x32_bf16(ah, Bl[d][0], a0, 0, 0, 0);
      a1 = __builtin_amdgcn_mfma_f32_16x16x32_bf16(ah, Bh[d][1], a1, 0, 0, 0);
      a1 = __builtin_amdgcn_mfma_f32_16x16x32_bf16(al, Bh[d][1], a1, 0, 0, 0);
      a1 = __builtin_amdgcn_mfma_f32_16x16x32_bf16(ah, Bl[d][1], a1, 0, 0, 0);
#pragma unroll
      for (int r = 0; r < 4; ++r) {
        a0[r] = fmaxf(a0[r] + bias_v[d][0], 0.f);
        a1[r] = fmaxf(a1[r] + bias_v[d][1], 0.f);
      }
      if (d < 2) {
#pragma unroll
        for (int r = 0; r < 4; ++r) {
          myl[(g * 4 + r) * 36 + c] = a0[r];
          myl[(g * 4 + r) * 36 + 16 + c] = a1[r];
        }
#pragma unroll
        for (int e = 0; e < 8; ++e) {
          const float h = myl[c * 36 + g * 8 + e];
          short hh, ll; split2(h, hh, ll);
          ah[e] = hh; al[e] = ll;
        }
      } else {
        float mr[4];
        if (fl) {
          const uint32_t mw = *(const uint32_t*)((const uint8_t*)maskp + tb + g * 4);
          mr[0] = (mw & 0x000000FFu) ? 1.f : 0.f;
          mr[1] = (mw & 0x0000FF00u) ? 1.f : 0.f;
          mr[2] = (mw & 0x00FF0000u) ? 1.f : 0.f;
          mr[3] = (mw & 0xFF000000u) ? 1.f : 0.f;
        } else {
          const int4 mi = *(const int4*)((const int*)maskp + tb + g * 4);
          mr[0] = mi.x ? 1.f : 0.f;
          mr[1] = mi.y ? 1.f : 0.f;
          mr[2] = mi.z ? 1.f : 0.f;
          mr[3] = mi.w ? 1.f : 0.f;
        }
        if (!active) { mr[0] = mr[1] = mr[2] = mr[3] = 0.f; }
#pragma unroll
        for (int r = 0; r < 4; ++r) {
          acc0 = fmaf(mr[r], a0[r], acc0);
          acc1 = fmaf(mr[r], a1[r], acc1);
          cntv += mr[r];
        }
      }
    }
  }

  acc0 += __shfl_xor(acc0, 16); acc0 += __shfl_xor(acc0, 32);
  acc1 += __shfl_xor(acc1, 16); acc1 += __shfl_xor(acc1, 32);
  cntv += __shfl_xor(cntv, 16); cntv += __shfl_xor(cntv, 32);
  if (lane < 16) {
    red[wid * 33 + lane] = acc0;
    red[wid * 33 + 16 + lane] = acc1;
  }
  if (lane == 0) red[wid * 33 + 32] = cntv;
  __syncthreads();
  if (tid < 33) {
    partial[blk * 33 + tid] =
        red[tid] + red[33 + tid] + red[66 + tid] + red[99 + tid];
  }
}

// --- 4. reduce partials -> rep_bias[b][n] = b_lin[n] + sum/cnt ---
__global__ void k_rep(const float* __restrict__ partial,
                      const float* __restrict__ b_lin,
                      float* __restrict__ rep_bias) {
  const int b = blockIdx.x, n = threadIdx.x;  // 16 x 32
  float sum = 0.f, cnt = 0.f;
  for (int s = 0; s < 32; ++s) {
    sum += partial[(b * 32 + s) * 33 + n];
    cnt += partial[(b * 32 + s) * 33 + 32];
  }
  rep_bias[b * 32 + n] = b_lin[n] + sum / cnt;
}

// --- 5. main pass: swapped MFMA + K-permuted weights ---
// R9 -> R10 deltas: bias via MFMA C-operand (refrag is relu-only),
// unified byte-mask path (stride fl?1:4), __launch_bounds__(256,4) to fit
// under the 128-total-register occupancy cliff (64/128/256 steps, m69).
__global__ __launch_bounds__(256, 4) void k_scale(
    const float* __restrict__ md, const void* __restrict__ maskp,
    const int* __restrict__ flag,
    const float* __restrict__ W_lin, const float* __restrict__ rep_bias,
    const float* __restrict__ Wd, const float* __restrict__ bd,
    const float* __restrict__ W_out, const float* __restrict__ b_out,
    float* __restrict__ out) {
  const int tid = threadIdx.x;
  const int wid = tid >> 6, lane = tid & 63;
  const int g = lane >> 4, c = lane & 15;
  const int job = blockIdx.x * 4 + wid;       // 6144 jobs x 256 positions
  const int b = job / 384;
  const size_t pos0 = (size_t)job * 256;
  const bool gLt2 = (g < 2);
  // unified mask: value lives in LSB byte for both int32-0/1 and byte masks
  const size_t mstride = flag[0] ? 1 : 4;
  const uint8_t* mbase = (const uint8_t*)maskp;

  // input-layer A-frags (channels 0-5 + rep_bias in k-slots 6,7)
  bf16x8 AW[2];
#pragma unroll
  for (int ct = 0; ct < 2; ++ct) {
    const float rb = rep_bias[b * 32 + ct * 16 + c];
    short rbh, rbl; split2(rb, rbh, rbl);
#pragma unroll
    for (int e = 0; e < 8; ++e) {
      short v = 0;
      if (e < 6) {
        short wh, wl; split2(W_lin[e * 32 + ct * 16 + c], wh, wl);
        v = gLt2 ? wh : wl;
      } else if (g == 0) {
        v = (e == 6) ? rbh : rbl;
      }
      AW[ct][e] = v;
    }
  }

  // hidden-layer A-frags with permuted K: slot (g,e) <- feat finv(g,e)
  bf16x8 AhW[3][2], AlW[3][2];
#pragma unroll
  for (int d = 0; d < 3; ++d)
#pragma unroll
    for (int ct = 0; ct < 2; ++ct)
#pragma unroll
      for (int e = 0; e < 8; ++e) {
        const int f = (e < 4) ? (4 * g + e) : (16 + 4 * g + (e - 4));
        short hh, ll; split2(Wd[d * 1024 + f * 32 + ct * 16 + c], hh, ll);
        AhW[d][ct][e] = hh; AlW[d][ct][e] = ll;
      }
  // biases as f32x4 -> used directly as the first MFMA's C operand
  f32x4 bsA[3], bsB[3];
#pragma unroll
  for (int d = 0; d < 3; ++d)
#pragma unroll
    for (int r = 0; r < 4; ++r) {
      bsA[d][r] = bd[d * 32 + 4 * g + r];
      bsB[d][r] = bd[d * 32 + 16 + 4 * g + r];
    }
  f32x4 woA, woB;
#pragma unroll
  for (int r = 0; r < 4; ++r) {
    woA[r] = W_out[4 * g + r];
    woB[r] = W_out[16 + 4 * g + r];
  }
  const float bo = b_out[0];
  const uint32_t bias_word = (g == 0) ? 0x00003F80u : 0u;

  // prefetch tile 0
  float mv[6];
  uint32_t mk;
  {
    const float* mrow = md + (pos0 + c) * 6;
    const float2 a01 = *(const float2*)(mrow);
    const float2 a23 = *(const float2*)(mrow + 2);
    const float2 a45 = *(const float2*)(mrow + 4);
    mv[0] = a01.x; mv[1] = a01.y; mv[2] = a23.x;
    mv[3] = a23.y; mv[4] = a45.x; mv[5] = a45.y;
    mk = mbase[(pos0 + c) * mstride];
  }

  const f32x4 z = {0.f, 0.f, 0.f, 0.f};

  for (int t = 0; t < 16; ++t) {
    const size_t tb = pos0 + (size_t)t * 16;

    float mvn[6];
    uint32_t mkn = 0;
    if (t < 15) {
      const float* mrow = md + (tb + 16 + c) * 6;
      const float2 a01 = *(const float2*)(mrow);
      const float2 a23 = *(const float2*)(mrow + 2);
      const float2 a45 = *(const float2*)(mrow + 4);
      mvn[0] = a01.x; mvn[1] = a01.y; mvn[2] = a23.x;
      mvn[3] = a23.y; mvn[4] = a45.x; mvn[5] = a45.y;
      mkn = mbase[(tb + 16 + c) * mstride];
    }

    // B-frag (data): words 0-2 = hi or lo packed pairs by (g&1); word3 = bias
    FragU Bin;
    {
      uint32_t ph0, pl0, ph1, pl1, ph2, pl2;
      split_pk(mv[0], mv[1], ph0, pl0);
      split_pk(mv[2], mv[3], ph1, pl1);
      split_pk(mv[4], mv[5], ph2, pl2);
      Bin.u[0] = (g & 1) ? pl0 : ph0;
      Bin.u[1] = (g & 1) ? pl1 : ph1;
      Bin.u[2] = (g & 1) ? pl2 : ph2;
      Bin.u[3] = bias_word;
    }

    // input layer: 2 MFMAs, exact (all 4 split products + rb in k-slots)
    f32x4 dT0 = __builtin_amdgcn_mfma_f32_16x16x32_bf16(AW[0], Bin.v, z, 0, 0, 0);
    f32x4 dT1 = __builtin_amdgcn_mfma_f32_16x16x32_bf16(AW[1], Bin.v, z, 0, 0, 0);

    // lane-local refrag (no relu/bias on input layer)
    bf16x8 Bh, Bl;
    {
      FragU H, L;
      split_pk(dT0[0], dT0[1], H.u[0], L.u[0]);
      split_pk(dT0[2], dT0[3], H.u[1], L.u[1]);
      split_pk(dT1[0], dT1[1], H.u[2], L.u[2]);
      split_pk(dT1[2], dT1[3], H.u[3], L.u[3]);
      Bh = H.v; Bl = L.v;
    }

#pragma unroll
    for (int d = 0; d < 3; ++d) {
      // bias enters as the C operand of the first MFMA of each chain
      dT0 = __builtin_amdgcn_mfma_f32_16x16x32_bf16(AhW[d][0], Bh, bsA[d], 0, 0, 0);
      dT0 = __builtin_amdgcn_mfma_f32_16x16x32_bf16(AlW[d][0], Bh, dT0, 0, 0, 0);
      dT0 = __builtin_amdgcn_mfma_f32_16x16x32_bf16(AhW[d][0], Bl, dT0, 0, 0, 0);
      dT1 = __builtin_amdgcn_mfma_f32_16x16x32_bf16(AhW[d][1], Bh, bsB[d], 0, 0, 0);
      dT1 = __builtin_amdgcn_mfma_f32_16x16x32_bf16(AlW[d][1], Bh, dT1, 0, 0, 0);
      dT1 = __builtin_amdgcn_mfma_f32_16x16x32_bf16(AhW[d][1], Bl, dT1, 0, 0, 0);
      if (d < 2) {
        // relu-only refrag (bias already accumulated)
        FragU H, L;
        const float x00 = fmaxf(dT0[0], 0.f), x01 = fmaxf(dT0[1], 0.f);
        const float x02 = fmaxf(dT0[2], 0.f), x03 = fmaxf(dT0[3], 0.f);
        const float x10 = fmaxf(dT1[0], 0.f), x11 = fmaxf(dT1[1], 0.f);
        const float x12 = fmaxf(dT1[2], 0.f), x13 = fmaxf(dT1[3], 0.f);
        split_pk(x00, x01, H.u[0], L.u[0]);
        split_pk(x02, x03, H.u[1], L.u[1]);
        split_pk(x10, x11, H.u[2], L.u[2]);
        split_pk(x12, x13, H.u[3], L.u[3]);
        Bh = H.v; Bl = L.v;
      } else {
        // epilogue: out[pos=c] = sum_f relu(H3[f][c]) * W_out[f] + bo
        float sum = 0.f;
#pragma unroll
        for (int r = 0; r < 4; ++r) {
          sum = fmaf(fmaxf(dT0[r], 0.f), woA[r], sum);
          sum = fmaf(fmaxf(dT1[r], 0.f), woB[r], sum);
        }
        sum += __shfl_xor(sum, 16);
        sum += __shfl_xor(sum, 32);
        if (g == 0) out[tb + c] = mk ? (sum + bo) : 0.0f;
      }
    }

#pragma unroll
    for (int i = 0; i < 6; ++i) mv[i] = mvn[i];
    mk = mkn;
  }
}

extern "C" void kernel_launch(void* const* d_in, const int* in_sizes, int n_in,
                              void* d_out, int out_size, void* d_ws, size_t ws_size,
                              hipStream_t stream) {
  const float* Imodel   = (const float*)d_in[0];
  const float* Iobs     = (const float*)d_in[1];
  const float* metadata = (const float*)d_in[2];
  const void*  mask     = d_in[3];
  const int*   sample_size = (const int*)d_in[4];
  const float* W_img_in = (const float*)d_in[5];
  const float* b_img_in = (const float*)d_in[6];
  const float* W_img    = (const float*)d_in[7];
  const float* b_img    = (const float*)d_in[8];
  const float* W_lin_in = (const float*)d_in[9];
  const float* b_lin_in = (const float*)d_in[10];
  const float* W_mlp    = (const float*)d_in[11];
  const float* b_mlp    = (const float*)d_in[12];
  const float* W_out    = (const float*)d_in[13];
  const float* b_out    = (const float*)d_in[14];
  float* out = (float*)d_out;

  char* ws = (char*)d_ws;
  int*   flag     = (int*)(ws + WS_FLAG);
  int*   sel      = (int*)(ws + WS_SEL);
  int*   vint     = (int*)(ws + WS_VINT);
  int*   vbyte    = (int*)(ws + WS_VBYTE);
  float* partial  = (float*)(ws + WS_PART);
  float* rep_bias = (float*)(ws + WS_REPB);

  k_valid<<<NROW / 4, 256, 0, stream>>>(mask, vint, vbyte);
  k_select<<<BB, 64, 0, stream>>>(mask, vint, vbyte, sample_size, flag, sel);
  k_image<<<512, 256, 0, stream>>>(Imodel, Iobs, metadata, mask, flag, sel,
                                   sample_size, W_img_in, b_img_in, W_img,
                                   b_img, partial);
  k_rep<<<BB, 32, 0, stream>>>(partial, b_lin_in, rep_bias);
  k_scale<<<1536, 256, 0, stream>>>(metadata, mask, flag, W_lin_in, rep_bias,
                                    W_mlp, b_mlp, W_out, b_out, out);
}

// Round 11
// 85.689 us; speedup vs baseline: 1.0348x; 1.0348x over previous
//
#include <hip/hip_runtime.h>
#include <hip/hip_bf16.h>
#include <stdint.h>

#define BB   16
#define JJ   256
#define KK   384
#define NROW (BB * JJ)               // 4096
#define NPOS ((size_t)BB * JJ * KK)  // 1572864

// ws layout (bytes)
#define WS_FLAG  0
#define WS_SEL   64                          // int[16*32]
#define WS_VINT  2176                        // int[4096]
#define WS_VBYTE (WS_VINT + NROW * 4)        // int[4096]
#define WS_PART  (WS_VBYTE + NROW * 4)       // float[512][33]
#define WS_REPB  (WS_PART + 512 * 33 * 4)    // float[16][32]

typedef float f32x4 __attribute__((ext_vector_type(4)));
typedef short bf16x8 __attribute__((ext_vector_type(8)));

struct FragU { union { bf16x8 v; uint32_t u[4]; }; };

__device__ __forceinline__ uint32_t rotl32(uint32_t x, int r) {
  return (x << r) | (x >> (32 - r));
}

__device__ __forceinline__ void threefry2x32_k42(uint32_t c0, uint32_t c1,
                                                 uint32_t& o0, uint32_t& o1) {
  const uint32_t ks0 = 0u, ks1 = 42u, ks2 = 0x1BD11BDAu ^ 0u ^ 42u;
  uint32_t x0 = c0 + ks0, x1 = c1 + ks1;
#define TFR(r) { x0 += x1; x1 = rotl32(x1, r); x1 ^= x0; }
  TFR(13) TFR(15) TFR(26) TFR(6)   x0 += ks1; x1 += ks2 + 1u;
  TFR(17) TFR(29) TFR(16) TFR(24)  x0 += ks2; x1 += ks0 + 2u;
  TFR(13) TFR(15) TFR(26) TFR(6)   x0 += ks0; x1 += ks1 + 3u;
  TFR(17) TFR(29) TFR(16) TFR(24)  x0 += ks1; x1 += ks2 + 4u;
  TFR(13) TFR(15) TFR(26) TFR(6)   x0 += ks2; x1 += ks0 + 5u;
#undef TFR
  o0 = x0; o1 = x1;
}

__device__ __forceinline__ uint32_t jax_bits(uint32_t t) {
  uint32_t o0, o1;
  threefry2x32_k42(0u, t, o0, o1);
  return o0 ^ o1;
}

// split f32 -> hi/lo bf16 (RNE), x ~= hi + lo
__device__ __forceinline__ void split2(float x, short& h, short& l) {
  const unsigned short hu = __builtin_bit_cast(unsigned short, __float2bfloat16(x));
  const float hf = __builtin_bit_cast(float, (uint32_t)hu << 16);
  h = (short)hu;
  l = (short)__builtin_bit_cast(unsigned short, __float2bfloat16(x - hf));
}

// split a pair -> packed hi-pair and lo-pair
__device__ __forceinline__ void split_pk(float x0, float x1,
                                         uint32_t& ph, uint32_t& pl) {
  const uint32_t h0 = (uint32_t)__builtin_bit_cast(unsigned short, __float2bfloat16(x0));
  const uint32_t h1 = (uint32_t)__builtin_bit_cast(unsigned short, __float2bfloat16(x1));
  ph = h0 | (h1 << 16);
  const float f0 = __builtin_bit_cast(float, h0 << 16);
  const float f1 = __builtin_bit_cast(float, h1 << 16);
  const uint32_t l0 = (uint32_t)__builtin_bit_cast(unsigned short, __float2bfloat16(x0 - f0));
  const uint32_t l1 = (uint32_t)__builtin_bit_cast(unsigned short, __float2bfloat16(x1 - f1));
  pl = l0 | (l1 << 16);
}

// lane-local refrag (K-permuted layout): Bh/Bl slots e<4 <- dT0, e>=4 <- dT1
__device__ __forceinline__ void refrag_ll(const f32x4 dT0, const f32x4 dT1,
                                          bf16x8& Bh, bf16x8& Bl) {
  FragU H, L;
  split_pk(dT0[0], dT0[1], H.u[0], L.u[0]);
  split_pk(dT0[2], dT0[3], H.u[1], L.u[1]);
  split_pk(dT1[0], dT1[1], H.u[2], L.u[2]);
  split_pk(dT1[2], dT1[3], H.u[3], L.u[3]);
  Bh = H.v; Bl = L.v;
}

__device__ __forceinline__ void refrag_br(f32x4 dT0, f32x4 dT1,
                                          const f32x4 b0, const f32x4 b1,
                                          bf16x8& Bh, bf16x8& Bl) {
#pragma unroll
  for (int r = 0; r < 4; ++r) {
    dT0[r] = fmaxf(dT0[r] + b0[r], 0.f);
    dT1[r] = fmaxf(dT1[r] + b1[r], 0.f);
  }
  refrag_ll(dT0, dT1, Bh, Bl);
}

// --- 1. row validity under BOTH mask-width interpretations ---
__global__ __launch_bounds__(256) void k_valid(const void* __restrict__ maskp,
                                               int* __restrict__ valid_int,
                                               int* __restrict__ valid_byte) {
  const int row = blockIdx.x * 4 + (threadIdx.x >> 6);
  const int lane = threadIdx.x & 63;
  const uint32_t* wi = (const uint32_t*)maskp + (size_t)row * 384;
  int v = 0;
#pragma unroll
  for (int i = 0; i < 6; ++i) v |= (wi[lane + i * 64] != 0u);
  const unsigned long long bi = __ballot(v);
  const uint32_t* wb = (const uint32_t*)maskp + (size_t)row * 96;
  int u = 0;
  for (int i = lane; i < 96; i += 64) u |= (wb[i] != 0u);
  const unsigned long long bu = __ballot(u);
  if (lane == 0) {
    valid_int[row] = (bi != 0ull) ? 1 : 0;
    valid_byte[row] = (bu != 0ull) ? 1 : 0;
  }
}

// --- 2. detect mask width + per-batch top-S gumbel selection ---
__global__ void k_select(const void* __restrict__ maskp,
                         const int* __restrict__ valid_int,
                         const int* __restrict__ valid_byte,
                         const int* __restrict__ sample_size,
                         int* __restrict__ flag_out, int* __restrict__ sel) {
  const int b = blockIdx.x, lane = threadIdx.x;  // 16 x 64
  const uint32_t* mw = (const uint32_t*)maskp;
  int big = 0;
#pragma unroll
  for (int i = 0; i < 16; ++i) big |= (mw[lane + i * 64] > 1u);
  const int fl = (__ballot(big) != 0ull) ? 1 : 0;
  if (b == 0 && lane == 0) flag_out[0] = fl;
  const int* valid = fl ? valid_byte : valid_int;

  uint32_t comp[4];
#pragma unroll
  for (int q = 0; q < 4; ++q) {
    const int j = lane * 4 + q;
    const uint32_t ub = jax_bits((uint32_t)(b * 256 + j)) >> 9;
    const uint32_t key = valid[b * 256 + j] ? (ub + 1u) : 0u;
    comp[q] = (key << 8) | (uint32_t)(255 - j);  // tie -> smaller j wins
  }
  int S = sample_size[0];
  if (S > 32) S = 32;
  for (int s = 0; s < S; ++s) {
    uint32_t wm = comp[0];
    wm = comp[1] > wm ? comp[1] : wm;
    wm = comp[2] > wm ? comp[2] : wm;
    wm = comp[3] > wm ? comp[3] : wm;
#pragma unroll
    for (int off = 32; off; off >>= 1) {
      const uint32_t o = __shfl_xor(wm, off);
      wm = o > wm ? o : wm;
    }
    if (wm == 0u) {
      if (lane == 0) sel[b * 32 + s] = 0;
    } else {
#pragma unroll
      for (int q = 0; q < 4; ++q) {
        if (comp[q] == wm) {
          sel[b * 32 + s] = 255 - (int)(comp[q] & 0xFFu);
          comp[q] = 0u;
        }
      }
    }
  }
  for (int s2 = S + lane; s2 < 32; s2 += 64) sel[b * 32 + s2] = 0;
}

// --- 3. image branch via split-bf16 MFMA (proven R5-era version) ---
__global__ __launch_bounds__(256, 1) void k_image(
    const float* __restrict__ Imodel, const float* __restrict__ Iobs,
    const float* __restrict__ md, const void* __restrict__ maskp,
    const int* __restrict__ flag, const int* __restrict__ sel,
    const int* __restrict__ sample_size,
    const float* __restrict__ W_in, const float* __restrict__ b_in,
    const float* __restrict__ Wd, const float* __restrict__ bd,
    float* __restrict__ partial) {
  __shared__ float lds_t[4][16 * 36];
  __shared__ float red[4 * 33];
  const int tid = threadIdx.x, wid = tid >> 6, lane = tid & 63;
  const int g = lane >> 4, c = lane & 15;
  const int blk = blockIdx.x;   // 512 = b*32 + s
  const int b = blk >> 5, s = blk & 31;
  const bool active = (s < sample_size[0]);
  const int j = sel[b * 32 + s] & 255;
  const size_t pos0 = ((size_t)(b * JJ + j)) * KK + (size_t)wid * 96;
  const int fl = flag[0];

  float Win[8][8];
#pragma unroll
  for (int cc = 0; cc < 8; ++cc)
#pragma unroll
    for (int e = 0; e < 8; ++e) Win[cc][e] = W_in[cc * 32 + g * 8 + e];
  float b0v[8];
#pragma unroll
  for (int e = 0; e < 8; ++e) b0v[e] = b_in[g * 8 + e];

  bf16x8 Bh[3][2], Bl[3][2];
#pragma unroll
  for (int d = 0; d < 3; ++d)
#pragma unroll
    for (int ct = 0; ct < 2; ++ct)
#pragma unroll
      for (int e = 0; e < 8; ++e) {
        const float w = Wd[d * 1024 + (g * 8 + e) * 32 + ct * 16 + c];
        short hh, ll; split2(w, hh, ll);
        Bh[d][ct][e] = hh; Bl[d][ct][e] = ll;
      }
  float bias_v[3][2];
#pragma unroll
  for (int d = 0; d < 3; ++d) {
    bias_v[d][0] = bd[d * 32 + c];
    bias_v[d][1] = bd[d * 32 + 16 + c];
  }
  float* myl = lds_t[wid];

  float acc0 = 0.f, acc1 = 0.f, cntv = 0.f;

  for (int t = 0; t < 6; ++t) {
    const size_t tb = pos0 + (size_t)t * 16;
    const size_t p = tb + c;
    float in[8];
    in[0] = Imodel[p];
    in[1] = Iobs[p];
    const float* mp = md + p * 6;
    const float2 v0 = *(const float2*)(mp);
    const float2 v1 = *(const float2*)(mp + 2);
    const float2 v2 = *(const float2*)(mp + 4);
    in[2] = v0.x; in[3] = v0.y; in[4] = v1.x; in[5] = v1.y;
    in[6] = v2.x; in[7] = v2.y;

    bf16x8 ah, al;
#pragma unroll
    for (int e = 0; e < 8; ++e) {
      float h = b0v[e];
#pragma unroll
      for (int cc = 0; cc < 8; ++cc) h = fmaf(in[cc], Win[cc][e], h);
      short hh, ll; split2(h, hh, ll);
      ah[e] = hh; al[e] = ll;
    }

#pragma unroll
    for (int d = 0; d < 3; ++d) {
      f32x4 a0 = {0.f, 0.f, 0.f, 0.f}, a1 = {0.f, 0.f, 0.f, 0.f};
      a0 = __builtin_amdgcn_mfma_f32_16x16x32_bf16(ah, Bh[d][0], a0, 0, 0, 0);
      a0 = __builtin_amdgcn_mfma_f32_16x16x32_bf16(al, Bh[d][0], a0, 0, 0, 0);
      a0 = __builtin_amdgcn_mfma_f32_16x16x32_bf16(ah, Bl[d][0], a0, 0, 0, 0);
      a1 = __builtin_amdgcn_mfma_f32_16x16x32_bf16(ah, Bh[d][1], a1, 0, 0, 0);
      a1 = __builtin_amdgcn_mfma_f32_16x16x32_bf16(al, Bh[d][1], a1, 0, 0, 0);
      a1 = __builtin_amdgcn_mfma_f32_16x16x32_bf16(ah, Bl[d][1], a1, 0, 0, 0);
#pragma unroll
      for (int r = 0; r < 4; ++r) {
        a0[r] = fmaxf(a0[r] + bias_v[d][0], 0.f);
        a1[r] = fmaxf(a1[r] + bias_v[d][1], 0.f);
      }
      if (d < 2) {
#pragma unroll
        for (int r = 0; r < 4; ++r) {
          myl[(g * 4 + r) * 36 + c] = a0[r];
          myl[(g * 4 + r) * 36 + 16 + c] = a1[r];
        }
#pragma unroll
        for (int e = 0; e < 8; ++e) {
          const float h = myl[c * 36 + g * 8 + e];
          short hh, ll; split2(h, hh, ll);
          ah[e] = hh; al[e] = ll;
        }
      } else {
        float mr[4];
        if (fl) {
          const uint32_t mw = *(const uint32_t*)((const uint8_t*)maskp + tb + g * 4);
          mr[0] = (mw & 0x000000FFu) ? 1.f : 0.f;
          mr[1] = (mw & 0x0000FF00u) ? 1.f : 0.f;
          mr[2] = (mw & 0x00FF0000u) ? 1.f : 0.f;
          mr[3] = (mw & 0xFF000000u) ? 1.f : 0.f;
        } else {
          const int4 mi = *(const int4*)((const int*)maskp + tb + g * 4);
          mr[0] = mi.x ? 1.f : 0.f;
          mr[1] = mi.y ? 1.f : 0.f;
          mr[2] = mi.z ? 1.f : 0.f;
          mr[3] = mi.w ? 1.f : 0.f;
        }
        if (!active) { mr[0] = mr[1] = mr[2] = mr[3] = 0.f; }
#pragma unroll
        for (int r = 0; r < 4; ++r) {
          acc0 = fmaf(mr[r], a0[r], acc0);
          acc1 = fmaf(mr[r], a1[r], acc1);
          cntv += mr[r];
        }
      }
    }
  }

  acc0 += __shfl_xor(acc0, 16); acc0 += __shfl_xor(acc0, 32);
  acc1 += __shfl_xor(acc1, 16); acc1 += __shfl_xor(acc1, 32);
  cntv += __shfl_xor(cntv, 16); cntv += __shfl_xor(cntv, 32);
  if (lane < 16) {
    red[wid * 33 + lane] = acc0;
    red[wid * 33 + 16 + lane] = acc1;
  }
  if (lane == 0) red[wid * 33 + 32] = cntv;
  __syncthreads();
  if (tid < 33) {
    partial[blk * 33 + tid] =
        red[tid] + red[33 + tid] + red[66 + tid] + red[99 + tid];
  }
}

// --- 4. reduce partials -> rep_bias[b][n] = b_lin[n] + sum/cnt ---
__global__ void k_rep(const float* __restrict__ partial,
                      const float* __restrict__ b_lin,
                      float* __restrict__ rep_bias) {
  const int b = blockIdx.x, n = threadIdx.x;  // 16 x 32
  float sum = 0.f, cnt = 0.f;
  for (int s = 0; s < 32; ++s) {
    sum += partial[(b * 32 + s) * 33 + n];
    cnt += partial[(b * 32 + s) * 33 + 32];
  }
  rep_bias[b * 32 + n] = b_lin[n] + sum / cnt;
}

// --- 5. main pass: swapped MFMA + K-permuted weights, 2-tile ILP ---
// R10 -> R11: revert C-operand-bias & stride-mask (R9 semantics), add
// 2-independent-tile interleave (dual MFMA chains hide dep latency),
// __launch_bounds__(256,3) (170-reg budget). No PIN (R8's poison).
__global__ __launch_bounds__(256, 3) void k_scale(
    const float* __restrict__ md, const void* __restrict__ maskp,
    const int* __restrict__ flag,
    const float* __restrict__ W_lin, const float* __restrict__ rep_bias,
    const float* __restrict__ Wd, const float* __restrict__ bd,
    const float* __restrict__ W_out, const float* __restrict__ b_out,
    float* __restrict__ out) {
  const int tid = threadIdx.x;
  const int wid = tid >> 6, lane = tid & 63;
  const int g = lane >> 4, c = lane & 15;
  const int job = blockIdx.x * 4 + wid;       // 6144 jobs x 256 positions
  const int b = job / 384;
  const size_t pos0 = (size_t)job * 256;
  const int fl = flag[0];
  const bool gLt2 = (g < 2);

  // input-layer A-frags (channels 0-5 + rep_bias in k-slots 6,7)
  bf16x8 AW[2];
#pragma unroll
  for (int ct = 0; ct < 2; ++ct) {
    const float rb = rep_bias[b * 32 + ct * 16 + c];
    short rbh, rbl; split2(rb, rbh, rbl);
#pragma unroll
    for (int e = 0; e < 8; ++e) {
      short v = 0;
      if (e < 6) {
        short wh, wl; split2(W_lin[e * 32 + ct * 16 + c], wh, wl);
        v = gLt2 ? wh : wl;
      } else if (g == 0) {
        v = (e == 6) ? rbh : rbl;
      }
      AW[ct][e] = v;
    }
  }

  // hidden-layer A-frags with permuted K: slot (g,e) <- feat finv(g,e)
  bf16x8 AhW[3][2], AlW[3][2];
#pragma unroll
  for (int d = 0; d < 3; ++d)
#pragma unroll
    for (int ct = 0; ct < 2; ++ct)
#pragma unroll
      for (int e = 0; e < 8; ++e) {
        const int f = (e < 4) ? (4 * g + e) : (16 + 4 * g + (e - 4));
        short hh, ll; split2(Wd[d * 1024 + f * 32 + ct * 16 + c], hh, ll);
        AhW[d][ct][e] = hh; AlW[d][ct][e] = ll;
      }
  f32x4 bsA[3], bsB[3];
#pragma unroll
  for (int d = 0; d < 3; ++d)
#pragma unroll
    for (int r = 0; r < 4; ++r) {
      bsA[d][r] = bd[d * 32 + 4 * g + r];
      bsB[d][r] = bd[d * 32 + 16 + 4 * g + r];
    }
  f32x4 woA, woB;
#pragma unroll
  for (int r = 0; r < 4; ++r) {
    woA[r] = W_out[4 * g + r];
    woB[r] = W_out[16 + 4 * g + r];
  }
  const float bo = b_out[0];
  const uint32_t bias_word = (g == 0) ? 0x00003F80u : 0u;

  // prefetch pair 0 (tiles 0,1)
  float mvA[6], mvB[6];
  uint32_t mkA, mkB;
  {
    const float* ra = md + (pos0 + c) * 6;
    const float2 a01 = *(const float2*)(ra);
    const float2 a23 = *(const float2*)(ra + 2);
    const float2 a45 = *(const float2*)(ra + 4);
    mvA[0] = a01.x; mvA[1] = a01.y; mvA[2] = a23.x;
    mvA[3] = a23.y; mvA[4] = a45.x; mvA[5] = a45.y;
    const float* rb2 = md + (pos0 + 16 + c) * 6;
    const float2 b01 = *(const float2*)(rb2);
    const float2 b23 = *(const float2*)(rb2 + 2);
    const float2 b45 = *(const float2*)(rb2 + 4);
    mvB[0] = b01.x; mvB[1] = b01.y; mvB[2] = b23.x;
    mvB[3] = b23.y; mvB[4] = b45.x; mvB[5] = b45.y;
    if (fl) {
      mkA = (uint32_t)((const uint8_t*)maskp)[pos0 + c];
      mkB = (uint32_t)((const uint8_t*)maskp)[pos0 + 16 + c];
    } else {
      mkA = ((const uint32_t*)maskp)[pos0 + c];
      mkB = ((const uint32_t*)maskp)[pos0 + 16 + c];
    }
  }

  const f32x4 z = {0.f, 0.f, 0.f, 0.f};

  for (int tp = 0; tp < 8; ++tp) {
    const size_t tbA = pos0 + (size_t)tp * 32;
    const size_t tbB = tbA + 16;

    // prefetch next pair (hidden under this pair's compute)
    float nvA[6] = {0, 0, 0, 0, 0, 0}, nvB[6] = {0, 0, 0, 0, 0, 0};
    uint32_t nkA = 0, nkB = 0;
    if (tp < 7) {
      const float* ra = md + (tbA + 32 + c) * 6;
      const float2 a01 = *(const float2*)(ra);
      const float2 a23 = *(const float2*)(ra + 2);
      const float2 a45 = *(const float2*)(ra + 4);
      nvA[0] = a01.x; nvA[1] = a01.y; nvA[2] = a23.x;
      nvA[3] = a23.y; nvA[4] = a45.x; nvA[5] = a45.y;
      const float* rb2 = md + (tbA + 48 + c) * 6;
      const float2 b01 = *(const float2*)(rb2);
      const float2 b23 = *(const float2*)(rb2 + 2);
      const float2 b45 = *(const float2*)(rb2 + 4);
      nvB[0] = b01.x; nvB[1] = b01.y; nvB[2] = b23.x;
      nvB[3] = b23.y; nvB[4] = b45.x; nvB[5] = b45.y;
      if (fl) {
        nkA = (uint32_t)((const uint8_t*)maskp)[tbA + 32 + c];
        nkB = (uint32_t)((const uint8_t*)maskp)[tbA + 48 + c];
      } else {
        nkA = ((const uint32_t*)maskp)[tbA + 32 + c];
        nkB = ((const uint32_t*)maskp)[tbA + 48 + c];
      }
    }

    // B-frags for both tiles: words 0-2 hi/lo packed pairs by (g&1), w3 bias
    FragU BinA, BinB;
    {
      uint32_t ph0, pl0, ph1, pl1, ph2, pl2;
      split_pk(mvA[0], mvA[1], ph0, pl0);
      split_pk(mvA[2], mvA[3], ph1, pl1);
      split_pk(mvA[4], mvA[5], ph2, pl2);
      BinA.u[0] = (g & 1) ? pl0 : ph0;
      BinA.u[1] = (g & 1) ? pl1 : ph1;
      BinA.u[2] = (g & 1) ? pl2 : ph2;
      BinA.u[3] = bias_word;
      split_pk(mvB[0], mvB[1], ph0, pl0);
      split_pk(mvB[2], mvB[3], ph1, pl1);
      split_pk(mvB[4], mvB[5], ph2, pl2);
      BinB.u[0] = (g & 1) ? pl0 : ph0;
      BinB.u[1] = (g & 1) ? pl1 : ph1;
      BinB.u[2] = (g & 1) ? pl2 : ph2;
      BinB.u[3] = bias_word;
    }

    // input layer: 2 MFMAs per tile, interleaved A/B chains
    f32x4 dT0A = __builtin_amdgcn_mfma_f32_16x16x32_bf16(AW[0], BinA.v, z, 0, 0, 0);
    f32x4 dT0B = __builtin_amdgcn_mfma_f32_16x16x32_bf16(AW[0], BinB.v, z, 0, 0, 0);
    f32x4 dT1A = __builtin_amdgcn_mfma_f32_16x16x32_bf16(AW[1], BinA.v, z, 0, 0, 0);
    f32x4 dT1B = __builtin_amdgcn_mfma_f32_16x16x32_bf16(AW[1], BinB.v, z, 0, 0, 0);

    bf16x8 BhA, BlA, BhB, BlB;
    refrag_ll(dT0A, dT1A, BhA, BlA);
    refrag_ll(dT0B, dT1B, BhB, BlB);

#pragma unroll
    for (int d = 0; d < 3; ++d) {
      dT0A = __builtin_amdgcn_mfma_f32_16x16x32_bf16(AhW[d][0], BhA, z, 0, 0, 0);
      dT0B = __builtin_amdgcn_mfma_f32_16x16x32_bf16(AhW[d][0], BhB, z, 0, 0, 0);
      dT1A = __builtin_amdgcn_mfma_f32_16x16x32_bf16(AhW[d][1], BhA, z, 0, 0, 0);
      dT1B = __builtin_amdgcn_mfma_f32_16x16x32_bf16(AhW[d][1], BhB, z, 0, 0, 0);
      dT0A = __builtin_amdgcn_mfma_f32_16x16x32_bf16(AlW[d][0], BhA, dT0A, 0, 0, 0);
      dT0B = __builtin_amdgcn_mfma_f32_16x16x32_bf16(AlW[d][0], BhB, dT0B, 0, 0, 0);
      dT1A = __builtin_amdgcn_mfma_f32_16x16x32_bf16(AlW[d][1], BhA, dT1A, 0, 0, 0);
      dT1B = __builtin_amdgcn_mfma_f32_16x16x32_bf16(AlW[d][1], BhB, dT1B, 0, 0, 0);
      dT0A = __builtin_amdgcn_mfma_f32_16x16x32_bf16(AhW[d][0], BlA, dT0A, 0, 0, 0);
      dT0B = __builtin_amdgcn_mfma_f32_16x16x32_bf16(AhW[d][0], BlB, dT0B, 0, 0, 0);
      dT1A = __builtin_amdgcn_mfma_f32_16x16x32_bf16(AhW[d][1], BlA, dT1A, 0, 0, 0);
      dT1B = __builtin_amdgcn_mfma_f32_16x16x32_bf16(AhW[d][1], BlB, dT1B, 0, 0, 0);
      if (d < 2) {
        refrag_br(dT0A, dT1A, bsA[d], bsB[d], BhA, BlA);
        refrag_br(dT0B, dT1B, bsA[d], bsB[d], BhB, BlB);
      } else {
        float sumA = 0.f, sumB = 0.f;
#pragma unroll
        for (int r = 0; r < 4; ++r) {
          sumA = fmaf(fmaxf(dT0A[r] + bsA[2][r], 0.f), woA[r], sumA);
          sumA = fmaf(fmaxf(dT1A[r] + bsB[2][r], 0.f), woB[r], sumA);
          sumB = fmaf(fmaxf(dT0B[r] + bsA[2][r], 0.f), woA[r], sumB);
          sumB = fmaf(fmaxf(dT1B[r] + bsB[2][r], 0.f), woB[r], sumB);
        }
        sumA += __shfl_xor(sumA, 16);
        sumA += __shfl_xor(sumA, 32);
        sumB += __shfl_xor(sumB, 16);
        sumB += __shfl_xor(sumB, 32);
        if (g == 0) {
          out[tbA + c] = mkA ? (sumA + bo) : 0.0f;
          out[tbB + c] = mkB ? (sumB + bo) : 0.0f;
        }
      }
    }

#pragma unroll
    for (int i = 0; i < 6; ++i) { mvA[i] = nvA[i]; mvB[i] = nvB[i]; }
    mkA = nkA; mkB = nkB;
  }
}

extern "C" void kernel_launch(void* const* d_in, const int* in_sizes, int n_in,
                              void* d_out, int out_size, void* d_ws, size_t ws_size,
                              hipStream_t stream) {
  const float* Imodel   = (const float*)d_in[0];
  const float* Iobs     = (const float*)d_in[1];
  const float* metadata = (const float*)d_in[2];
  const void*  mask     = d_in[3];
  const int*   sample_size = (const int*)d_in[4];
  const float* W_img_in = (const float*)d_in[5];
  const float* b_img_in = (const float*)d_in[6];
  const float* W_img    = (const float*)d_in[7];
  const float* b_img    = (const float*)d_in[8];
  const float* W_lin_in = (const float*)d_in[9];
  const float* b_lin_in = (const float*)d_in[10];
  const float* W_mlp    = (const float*)d_in[11];
  const float* b_mlp    = (const float*)d_in[12];
  const float* W_out    = (const float*)d_in[13];
  const float* b_out    = (const float*)d_in[14];
  float* out = (float*)d_out;

  char* ws = (char*)d_ws;
  int*   flag     = (int*)(ws + WS_FLAG);
  int*   sel      = (int*)(ws + WS_SEL);
  int*   vint     = (int*)(ws + WS_VINT);
  int*   vbyte    = (int*)(ws + WS_VBYTE);
  float* partial  = (float*)(ws + WS_PART);
  float* rep_bias = (float*)(ws + WS_REPB);

  k_valid<<<NROW / 4, 256, 0, stream>>>(mask, vint, vbyte);
  k_select<<<BB, 64, 0, stream>>>(mask, vint, vbyte, sample_size, flag, sel);
  k_image<<<512, 256, 0, stream>>>(Imodel, Iobs, metadata, mask, flag, sel,
                                   sample_size, W_img_in, b_img_in, W_img,
                                   b_img, partial);
  k_rep<<<BB, 32, 0, stream>>>(partial, b_lin_in, rep_bias);
  k_scale<<<1536, 256, 0, stream>>>(metadata, mask, flag, W_lin_in, rep_bias,
                                    W_mlp, b_mlp, W_out, b_out, out);
}

// Round 12
// 77.159 us; speedup vs baseline: 1.1492x; 1.1106x over previous
//
#include <hip/hip_runtime.h>
#include <hip/hip_bf16.h>
#include <stdint.h>

#define BB   16
#define JJ   256
#define KK   384
#define NROW (BB * JJ)               // 4096
#define NPOS ((size_t)BB * JJ * KK)  // 1572864

// ws layout (bytes)
#define WS_FLAG  0
#define WS_SEL   64                          // int[16*32]
#define WS_VINT  2176                        // int[4096]
#define WS_VBYTE (WS_VINT + NROW * 4)        // int[4096]
#define WS_PART  (WS_VBYTE + NROW * 4)       // float[512][33]
#define WS_REPB  (WS_PART + 512 * 33 * 4)    // float[16][32]

typedef float f32x4 __attribute__((ext_vector_type(4)));
typedef short bf16x8 __attribute__((ext_vector_type(8)));

struct FragU { union { bf16x8 v; uint32_t u[4]; }; };

__device__ __forceinline__ uint32_t rotl32(uint32_t x, int r) {
  return (x << r) | (x >> (32 - r));
}

__device__ __forceinline__ void threefry2x32_k42(uint32_t c0, uint32_t c1,
                                                 uint32_t& o0, uint32_t& o1) {
  const uint32_t ks0 = 0u, ks1 = 42u, ks2 = 0x1BD11BDAu ^ 0u ^ 42u;
  uint32_t x0 = c0 + ks0, x1 = c1 + ks1;
#define TFR(r) { x0 += x1; x1 = rotl32(x1, r); x1 ^= x0; }
  TFR(13) TFR(15) TFR(26) TFR(6)   x0 += ks1; x1 += ks2 + 1u;
  TFR(17) TFR(29) TFR(16) TFR(24)  x0 += ks2; x1 += ks0 + 2u;
  TFR(13) TFR(15) TFR(26) TFR(6)   x0 += ks0; x1 += ks1 + 3u;
  TFR(17) TFR(29) TFR(16) TFR(24)  x0 += ks1; x1 += ks2 + 4u;
  TFR(13) TFR(15) TFR(26) TFR(6)   x0 += ks2; x1 += ks0 + 5u;
#undef TFR
  o0 = x0; o1 = x1;
}

__device__ __forceinline__ uint32_t jax_bits(uint32_t t) {
  uint32_t o0, o1;
  threefry2x32_k42(0u, t, o0, o1);
  return o0 ^ o1;
}

// exact SW-RNE split (setup/one-time use): x ~= hi + lo, both RNE
__device__ __forceinline__ void split2(float x, short& h, short& l) {
  const unsigned short hu = __builtin_bit_cast(unsigned short, __float2bfloat16(x));
  const float hf = __builtin_bit_cast(float, (uint32_t)hu << 16);
  h = (short)hu;
  l = (short)__builtin_bit_cast(unsigned short, __float2bfloat16(x - hf));
}

// FAST activation split (hot loop): hi = truncated bf16 prefix (exact bit op,
// packed with one v_perm_b32); lo = RNE(x - hi) via HW v_cvt_pk_bf16_f32.
// ph = {bf16t(x1), bf16t(x0)}, pl = {bf16(r1), bf16(r0)}
__device__ __forceinline__ void split_pk(float x0, float x1,
                                         uint32_t& ph, uint32_t& pl) {
  const uint32_t u0 = __builtin_bit_cast(uint32_t, x0);
  const uint32_t u1 = __builtin_bit_cast(uint32_t, x1);
  ph = __builtin_amdgcn_perm(u1, u0, 0x07060302u);  // hi16(u1):hi16(u0)
  const float r0 = x0 - __builtin_bit_cast(float, u0 & 0xFFFF0000u);
  const float r1 = x1 - __builtin_bit_cast(float, u1 & 0xFFFF0000u);
  uint32_t p;
  asm("v_cvt_pk_bf16_f32 %0, %1, %2" : "=v"(p) : "v"(r0), "v"(r1));
  pl = p;
}

// lane-local refrag (K-permuted layout): Bh/Bl slots e<4 <- dT0, e>=4 <- dT1
__device__ __forceinline__ void refrag_ll(const f32x4 dT0, const f32x4 dT1,
                                          bf16x8& Bh, bf16x8& Bl) {
  FragU H, L;
  split_pk(dT0[0], dT0[1], H.u[0], L.u[0]);
  split_pk(dT0[2], dT0[3], H.u[1], L.u[1]);
  split_pk(dT1[0], dT1[1], H.u[2], L.u[2]);
  split_pk(dT1[2], dT1[3], H.u[3], L.u[3]);
  Bh = H.v; Bl = L.v;
}

__device__ __forceinline__ void refrag_br(f32x4 dT0, f32x4 dT1,
                                          const f32x4 b0, const f32x4 b1,
                                          bf16x8& Bh, bf16x8& Bl) {
#pragma unroll
  for (int r = 0; r < 4; ++r) {
    dT0[r] = fmaxf(dT0[r] + b0[r], 0.f);
    dT1[r] = fmaxf(dT1[r] + b1[r], 0.f);
  }
  refrag_ll(dT0, dT1, Bh, Bl);
}

// --- 1. row validity under BOTH mask-width interpretations ---
__global__ __launch_bounds__(256) void k_valid(const void* __restrict__ maskp,
                                               int* __restrict__ valid_int,
                                               int* __restrict__ valid_byte) {
  const int row = blockIdx.x * 4 + (threadIdx.x >> 6);
  const int lane = threadIdx.x & 63;
  const uint32_t* wi = (const uint32_t*)maskp + (size_t)row * 384;
  int v = 0;
#pragma unroll
  for (int i = 0; i < 6; ++i) v |= (wi[lane + i * 64] != 0u);
  const unsigned long long bi = __ballot(v);
  const uint32_t* wb = (const uint32_t*)maskp + (size_t)row * 96;
  int u = 0;
  for (int i = lane; i < 96; i += 64) u |= (wb[i] != 0u);
  const unsigned long long bu = __ballot(u);
  if (lane == 0) {
    valid_int[row] = (bi != 0ull) ? 1 : 0;
    valid_byte[row] = (bu != 0ull) ? 1 : 0;
  }
}

// --- 2. detect mask width + per-batch top-S gumbel selection ---
__global__ void k_select(const void* __restrict__ maskp,
                         const int* __restrict__ valid_int,
                         const int* __restrict__ valid_byte,
                         const int* __restrict__ sample_size,
                         int* __restrict__ flag_out, int* __restrict__ sel) {
  const int b = blockIdx.x, lane = threadIdx.x;  // 16 x 64
  const uint32_t* mw = (const uint32_t*)maskp;
  int big = 0;
#pragma unroll
  for (int i = 0; i < 16; ++i) big |= (mw[lane + i * 64] > 1u);
  const int fl = (__ballot(big) != 0ull) ? 1 : 0;
  if (b == 0 && lane == 0) flag_out[0] = fl;
  const int* valid = fl ? valid_byte : valid_int;

  uint32_t comp[4];
#pragma unroll
  for (int q = 0; q < 4; ++q) {
    const int j = lane * 4 + q;
    const uint32_t ub = jax_bits((uint32_t)(b * 256 + j)) >> 9;
    const uint32_t key = valid[b * 256 + j] ? (ub + 1u) : 0u;
    comp[q] = (key << 8) | (uint32_t)(255 - j);  // tie -> smaller j wins
  }
  int S = sample_size[0];
  if (S > 32) S = 32;
  for (int s = 0; s < S; ++s) {
    uint32_t wm = comp[0];
    wm = comp[1] > wm ? comp[1] : wm;
    wm = comp[2] > wm ? comp[2] : wm;
    wm = comp[3] > wm ? comp[3] : wm;
#pragma unroll
    for (int off = 32; off; off >>= 1) {
      const uint32_t o = __shfl_xor(wm, off);
      wm = o > wm ? o : wm;
    }
    if (wm == 0u) {
      if (lane == 0) sel[b * 32 + s] = 0;
    } else {
#pragma unroll
      for (int q = 0; q < 4; ++q) {
        if (comp[q] == wm) {
          sel[b * 32 + s] = 255 - (int)(comp[q] & 0xFFu);
          comp[q] = 0u;
        }
      }
    }
  }
  for (int s2 = S + lane; s2 < 32; s2 += 64) sel[b * 32 + s2] = 0;
}

// --- 3. image branch via split-bf16 MFMA (proven R5-era version) ---
__global__ __launch_bounds__(256, 1) void k_image(
    const float* __restrict__ Imodel, const float* __restrict__ Iobs,
    const float* __restrict__ md, const void* __restrict__ maskp,
    const int* __restrict__ flag, const int* __restrict__ sel,
    const int* __restrict__ sample_size,
    const float* __restrict__ W_in, const float* __restrict__ b_in,
    const float* __restrict__ Wd, const float* __restrict__ bd,
    float* __restrict__ partial) {
  __shared__ float lds_t[4][16 * 36];
  __shared__ float red[4 * 33];
  const int tid = threadIdx.x, wid = tid >> 6, lane = tid & 63;
  const int g = lane >> 4, c = lane & 15;
  const int blk = blockIdx.x;   // 512 = b*32 + s
  const int b = blk >> 5, s = blk & 31;
  const bool active = (s < sample_size[0]);
  const int j = sel[b * 32 + s] & 255;
  const size_t pos0 = ((size_t)(b * JJ + j)) * KK + (size_t)wid * 96;
  const int fl = flag[0];

  float Win[8][8];
#pragma unroll
  for (int cc = 0; cc < 8; ++cc)
#pragma unroll
    for (int e = 0; e < 8; ++e) Win[cc][e] = W_in[cc * 32 + g * 8 + e];
  float b0v[8];
#pragma unroll
  for (int e = 0; e < 8; ++e) b0v[e] = b_in[g * 8 + e];

  bf16x8 Bh[3][2], Bl[3][2];
#pragma unroll
  for (int d = 0; d < 3; ++d)
#pragma unroll
    for (int ct = 0; ct < 2; ++ct)
#pragma unroll
      for (int e = 0; e < 8; ++e) {
        const float w = Wd[d * 1024 + (g * 8 + e) * 32 + ct * 16 + c];
        short hh, ll; split2(w, hh, ll);
        Bh[d][ct][e] = hh; Bl[d][ct][e] = ll;
      }
  float bias_v[3][2];
#pragma unroll
  for (int d = 0; d < 3; ++d) {
    bias_v[d][0] = bd[d * 32 + c];
    bias_v[d][1] = bd[d * 32 + 16 + c];
  }
  float* myl = lds_t[wid];

  float acc0 = 0.f, acc1 = 0.f, cntv = 0.f;

  for (int t = 0; t < 6; ++t) {
    const size_t tb = pos0 + (size_t)t * 16;
    const size_t p = tb + c;
    float in[8];
    in[0] = Imodel[p];
    in[1] = Iobs[p];
    const float* mp = md + p * 6;
    const float2 v0 = *(const float2*)(mp);
    const float2 v1 = *(const float2*)(mp + 2);
    const float2 v2 = *(const float2*)(mp + 4);
    in[2] = v0.x; in[3] = v0.y; in[4] = v1.x; in[5] = v1.y;
    in[6] = v2.x; in[7] = v2.y;

    bf16x8 ah, al;
#pragma unroll
    for (int e = 0; e < 8; ++e) {
      float h = b0v[e];
#pragma unroll
      for (int cc = 0; cc < 8; ++cc) h = fmaf(in[cc], Win[cc][e], h);
      short hh, ll; split2(h, hh, ll);
      ah[e] = hh; al[e] = ll;
    }

#pragma unroll
    for (int d = 0; d < 3; ++d) {
      f32x4 a0 = {0.f, 0.f, 0.f, 0.f}, a1 = {0.f, 0.f, 0.f, 0.f};
      a0 = __builtin_amdgcn_mfma_f32_16x16x32_bf16(ah, Bh[d][0], a0, 0, 0, 0);
      a0 = __builtin_amdgcn_mfma_f32_16x16x32_bf16(al, Bh[d][0], a0, 0, 0, 0);
      a0 = __builtin_amdgcn_mfma_f32_16x16x32_bf16(ah, Bl[d][0], a0, 0, 0, 0);
      a1 = __builtin_amdgcn_mfma_f32_16x16x32_bf16(ah, Bh[d][1], a1, 0, 0, 0);
      a1 = __builtin_amdgcn_mfma_f32_16x16x32_bf16(al, Bh[d][1], a1, 0, 0, 0);
      a1 = __builtin_amdgcn_mfma_f32_16x16x32_bf16(ah, Bl[d][1], a1, 0, 0, 0);
#pragma unroll
      for (int r = 0; r < 4; ++r) {
        a0[r] = fmaxf(a0[r] + bias_v[d][0], 0.f);
        a1[r] = fmaxf(a1[r] + bias_v[d][1], 0.f);
      }
      if (d < 2) {
#pragma unroll
        for (int r = 0; r < 4; ++r) {
          myl[(g * 4 + r) * 36 + c] = a0[r];
          myl[(g * 4 + r) * 36 + 16 + c] = a1[r];
        }
#pragma unroll
        for (int e = 0; e < 8; ++e) {
          const float h = myl[c * 36 + g * 8 + e];
          short hh, ll; split2(h, hh, ll);
          ah[e] = hh; al[e] = ll;
        }
      } else {
        float mr[4];
        if (fl) {
          const uint32_t mw = *(const uint32_t*)((const uint8_t*)maskp + tb + g * 4);
          mr[0] = (mw & 0x000000FFu) ? 1.f : 0.f;
          mr[1] = (mw & 0x0000FF00u) ? 1.f : 0.f;
          mr[2] = (mw & 0x00FF0000u) ? 1.f : 0.f;
          mr[3] = (mw & 0xFF000000u) ? 1.f : 0.f;
        } else {
          const int4 mi = *(const int4*)((const int*)maskp + tb + g * 4);
          mr[0] = mi.x ? 1.f : 0.f;
          mr[1] = mi.y ? 1.f : 0.f;
          mr[2] = mi.z ? 1.f : 0.f;
          mr[3] = mi.w ? 1.f : 0.f;
        }
        if (!active) { mr[0] = mr[1] = mr[2] = mr[3] = 0.f; }
#pragma unroll
        for (int r = 0; r < 4; ++r) {
          acc0 = fmaf(mr[r], a0[r], acc0);
          acc1 = fmaf(mr[r], a1[r], acc1);
          cntv += mr[r];
        }
      }
    }
  }

  acc0 += __shfl_xor(acc0, 16); acc0 += __shfl_xor(acc0, 32);
  acc1 += __shfl_xor(acc1, 16); acc1 += __shfl_xor(acc1, 32);
  cntv += __shfl_xor(cntv, 16); cntv += __shfl_xor(cntv, 32);
  if (lane < 16) {
    red[wid * 33 + lane] = acc0;
    red[wid * 33 + 16 + lane] = acc1;
  }
  if (lane == 0) red[wid * 33 + 32] = cntv;
  __syncthreads();
  if (tid < 33) {
    partial[blk * 33 + tid] =
        red[tid] + red[33 + tid] + red[66 + tid] + red[99 + tid];
  }
}

// --- 4. reduce partials -> rep_bias[b][n] = b_lin[n] + sum/cnt ---
__global__ void k_rep(const float* __restrict__ partial,
                      const float* __restrict__ b_lin,
                      float* __restrict__ rep_bias) {
  const int b = blockIdx.x, n = threadIdx.x;  // 16 x 32
  float sum = 0.f, cnt = 0.f;
  for (int s = 0; s < 32; ++s) {
    sum += partial[(b * 32 + s) * 33 + n];
    cnt += partial[(b * 32 + s) * 33 + 32];
  }
  rep_bias[b * 32 + n] = b_lin[n] + sum / cnt;
}

// --- 5. main pass: swapped MFMA + K-permuted weights, 2-tile ILP ---
// R11 -> R12: activation splits via HW (v_perm_b32 trunc-hi + v_cvt_pk_bf16_f32
// lo) -> split_pk 24 insts -> 6. Weights keep exact SW-RNE split (setup only).
__global__ __launch_bounds__(256, 3) void k_scale(
    const float* __restrict__ md, const void* __restrict__ maskp,
    const int* __restrict__ flag,
    const float* __restrict__ W_lin, const float* __restrict__ rep_bias,
    const float* __restrict__ Wd, const float* __restrict__ bd,
    const float* __restrict__ W_out, const float* __restrict__ b_out,
    float* __restrict__ out) {
  const int tid = threadIdx.x;
  const int wid = tid >> 6, lane = tid & 63;
  const int g = lane >> 4, c = lane & 15;
  const int job = blockIdx.x * 4 + wid;       // 6144 jobs x 256 positions
  const int b = job / 384;
  const size_t pos0 = (size_t)job * 256;
  const int fl = flag[0];
  const bool gLt2 = (g < 2);

  // input-layer A-frags (channels 0-5 + rep_bias in k-slots 6,7)
  bf16x8 AW[2];
#pragma unroll
  for (int ct = 0; ct < 2; ++ct) {
    const float rb = rep_bias[b * 32 + ct * 16 + c];
    short rbh, rbl; split2(rb, rbh, rbl);
#pragma unroll
    for (int e = 0; e < 8; ++e) {
      short v = 0;
      if (e < 6) {
        short wh, wl; split2(W_lin[e * 32 + ct * 16 + c], wh, wl);
        v = gLt2 ? wh : wl;
      } else if (g == 0) {
        v = (e == 6) ? rbh : rbl;
      }
      AW[ct][e] = v;
    }
  }

  // hidden-layer A-frags with permuted K: slot (g,e) <- feat finv(g,e)
  bf16x8 AhW[3][2], AlW[3][2];
#pragma unroll
  for (int d = 0; d < 3; ++d)
#pragma unroll
    for (int ct = 0; ct < 2; ++ct)
#pragma unroll
      for (int e = 0; e < 8; ++e) {
        const int f = (e < 4) ? (4 * g + e) : (16 + 4 * g + (e - 4));
        short hh, ll; split2(Wd[d * 1024 + f * 32 + ct * 16 + c], hh, ll);
        AhW[d][ct][e] = hh; AlW[d][ct][e] = ll;
      }
  f32x4 bsA[3], bsB[3];
#pragma unroll
  for (int d = 0; d < 3; ++d)
#pragma unroll
    for (int r = 0; r < 4; ++r) {
      bsA[d][r] = bd[d * 32 + 4 * g + r];
      bsB[d][r] = bd[d * 32 + 16 + 4 * g + r];
    }
  f32x4 woA, woB;
#pragma unroll
  for (int r = 0; r < 4; ++r) {
    woA[r] = W_out[4 * g + r];
    woB[r] = W_out[16 + 4 * g + r];
  }
  const float bo = b_out[0];
  const uint32_t bias_word = (g == 0) ? 0x00003F80u : 0u;

  // prefetch pair 0 (tiles 0,1)
  float mvA[6], mvB[6];
  uint32_t mkA, mkB;
  {
    const float* ra = md + (pos0 + c) * 6;
    const float2 a01 = *(const float2*)(ra);
    const float2 a23 = *(const float2*)(ra + 2);
    const float2 a45 = *(const float2*)(ra + 4);
    mvA[0] = a01.x; mvA[1] = a01.y; mvA[2] = a23.x;
    mvA[3] = a23.y; mvA[4] = a45.x; mvA[5] = a45.y;
    const float* rb2 = md + (pos0 + 16 + c) * 6;
    const float2 b01 = *(const float2*)(rb2);
    const float2 b23 = *(const float2*)(rb2 + 2);
    const float2 b45 = *(const float2*)(rb2 + 4);
    mvB[0] = b01.x; mvB[1] = b01.y; mvB[2] = b23.x;
    mvB[3] = b23.y; mvB[4] = b45.x; mvB[5] = b45.y;
    if (fl) {
      mkA = (uint32_t)((const uint8_t*)maskp)[pos0 + c];
      mkB = (uint32_t)((const uint8_t*)maskp)[pos0 + 16 + c];
    } else {
      mkA = ((const uint32_t*)maskp)[pos0 + c];
      mkB = ((const uint32_t*)maskp)[pos0 + 16 + c];
    }
  }

  const f32x4 z = {0.f, 0.f, 0.f, 0.f};

  for (int tp = 0; tp < 8; ++tp) {
    const size_t tbA = pos0 + (size_t)tp * 32;
    const size_t tbB = tbA + 16;

    // prefetch next pair (hidden under this pair's compute)
    float nvA[6] = {0, 0, 0, 0, 0, 0}, nvB[6] = {0, 0, 0, 0, 0, 0};
    uint32_t nkA = 0, nkB = 0;
    if (tp < 7) {
      const float* ra = md + (tbA + 32 + c) * 6;
      const float2 a01 = *(const float2*)(ra);
      const float2 a23 = *(const float2*)(ra + 2);
      const float2 a45 = *(const float2*)(ra + 4);
      nvA[0] = a01.x; nvA[1] = a01.y; nvA[2] = a23.x;
      nvA[3] = a23.y; nvA[4] = a45.x; nvA[5] = a45.y;
      const float* rb2 = md + (tbA + 48 + c) * 6;
      const float2 b01 = *(const float2*)(rb2);
      const float2 b23 = *(const float2*)(rb2 + 2);
      const float2 b45 = *(const float2*)(rb2 + 4);
      nvB[0] = b01.x; nvB[1] = b01.y; nvB[2] = b23.x;
      nvB[3] = b23.y; nvB[4] = b45.x; nvB[5] = b45.y;
      if (fl) {
        nkA = (uint32_t)((const uint8_t*)maskp)[tbA + 32 + c];
        nkB = (uint32_t)((const uint8_t*)maskp)[tbA + 48 + c];
      } else {
        nkA = ((const uint32_t*)maskp)[tbA + 32 + c];
        nkB = ((const uint32_t*)maskp)[tbA + 48 + c];
      }
    }

    // B-frags for both tiles: words 0-2 hi/lo packed pairs by (g&1), w3 bias
    FragU BinA, BinB;
    {
      uint32_t ph0, pl0, ph1, pl1, ph2, pl2;
      split_pk(mvA[0], mvA[1], ph0, pl0);
      split_pk(mvA[2], mvA[3], ph1, pl1);
      split_pk(mvA[4], mvA[5], ph2, pl2);
      BinA.u[0] = (g & 1) ? pl0 : ph0;
      BinA.u[1] = (g & 1) ? pl1 : ph1;
      BinA.u[2] = (g & 1) ? pl2 : ph2;
      BinA.u[3] = bias_word;
      split_pk(mvB[0], mvB[1], ph0, pl0);
      split_pk(mvB[2], mvB[3], ph1, pl1);
      split_pk(mvB[4], mvB[5], ph2, pl2);
      BinB.u[0] = (g & 1) ? pl0 : ph0;
      BinB.u[1] = (g & 1) ? pl1 : ph1;
      BinB.u[2] = (g & 1) ? pl2 : ph2;
      BinB.u[3] = bias_word;
    }

    // input layer: 2 MFMAs per tile, interleaved A/B chains
    f32x4 dT0A = __builtin_amdgcn_mfma_f32_16x16x32_bf16(AW[0], BinA.v, z, 0, 0, 0);
    f32x4 dT0B = __builtin_amdgcn_mfma_f32_16x16x32_bf16(AW[0], BinB.v, z, 0, 0, 0);
    f32x4 dT1A = __builtin_amdgcn_mfma_f32_16x16x32_bf16(AW[1], BinA.v, z, 0, 0, 0);
    f32x4 dT1B = __builtin_amdgcn_mfma_f32_16x16x32_bf16(AW[1], BinB.v, z, 0, 0, 0);

    bf16x8 BhA, BlA, BhB, BlB;
    refrag_ll(dT0A, dT1A, BhA, BlA);
    refrag_ll(dT0B, dT1B, BhB, BlB);

#pragma unroll
    for (int d = 0; d < 3; ++d) {
      dT0A = __builtin_amdgcn_mfma_f32_16x16x32_bf16(AhW[d][0], BhA, z, 0, 0, 0);
      dT0B = __builtin_amdgcn_mfma_f32_16x16x32_bf16(AhW[d][0], BhB, z, 0, 0, 0);
      dT1A = __builtin_amdgcn_mfma_f32_16x16x32_bf16(AhW[d][1], BhA, z, 0, 0, 0);
      dT1B = __builtin_amdgcn_mfma_f32_16x16x32_bf16(AhW[d][1], BhB, z, 0, 0, 0);
      dT0A = __builtin_amdgcn_mfma_f32_16x16x32_bf16(AlW[d][0], BhA, dT0A, 0, 0, 0);
      dT0B = __builtin_amdgcn_mfma_f32_16x16x32_bf16(AlW[d][0], BhB, dT0B, 0, 0, 0);
      dT1A = __builtin_amdgcn_mfma_f32_16x16x32_bf16(AlW[d][1], BhA, dT1A, 0, 0, 0);
      dT1B = __builtin_amdgcn_mfma_f32_16x16x32_bf16(AlW[d][1], BhB, dT1B, 0, 0, 0);
      dT0A = __builtin_amdgcn_mfma_f32_16x16x32_bf16(AhW[d][0], BlA, dT0A, 0, 0, 0);
      dT0B = __builtin_amdgcn_mfma_f32_16x16x32_bf16(AhW[d][0], BlB, dT0B, 0, 0, 0);
      dT1A = __builtin_amdgcn_mfma_f32_16x16x32_bf16(AhW[d][1], BlA, dT1A, 0, 0, 0);
      dT1B = __builtin_amdgcn_mfma_f32_16x16x32_bf16(AhW[d][1], BlB, dT1B, 0, 0, 0);
      if (d < 2) {
        refrag_br(dT0A, dT1A, bsA[d], bsB[d], BhA, BlA);
        refrag_br(dT0B, dT1B, bsA[d], bsB[d], BhB, BlB);
      } else {
        float sumA = 0.f, sumB = 0.f;
#pragma unroll
        for (int r = 0; r < 4; ++r) {
          sumA = fmaf(fmaxf(dT0A[r] + bsA[2][r], 0.f), woA[r], sumA);
          sumA = fmaf(fmaxf(dT1A[r] + bsB[2][r], 0.f), woB[r], sumA);
          sumB = fmaf(fmaxf(dT0B[r] + bsA[2][r], 0.f), woA[r], sumB);
          sumB = fmaf(fmaxf(dT1B[r] + bsB[2][r], 0.f), woB[r], sumB);
        }
        sumA += __shfl_xor(sumA, 16);
        sumA += __shfl_xor(sumA, 32);
        sumB += __shfl_xor(sumB, 16);
        sumB += __shfl_xor(sumB, 32);
        if (g == 0) {
          out[tbA + c] = mkA ? (sumA + bo) : 0.0f;
          out[tbB + c] = mkB ? (sumB + bo) : 0.0f;
        }
      }
    }

#pragma unroll
    for (int i = 0; i < 6; ++i) { mvA[i] = nvA[i]; mvB[i] = nvB[i]; }
    mkA = nkA; mkB = nkB;
  }
}

extern "C" void kernel_launch(void* const* d_in, const int* in_sizes, int n_in,
                              void* d_out, int out_size, void* d_ws, size_t ws_size,
                              hipStream_t stream) {
  const float* Imodel   = (const float*)d_in[0];
  const float* Iobs     = (const float*)d_in[1];
  const float* metadata = (const float*)d_in[2];
  const void*  mask     = d_in[3];
  const int*   sample_size = (const int*)d_in[4];
  const float* W_img_in = (const float*)d_in[5];
  const float* b_img_in = (const float*)d_in[6];
  const float* W_img    = (const float*)d_in[7];
  const float* b_img    = (const float*)d_in[8];
  const float* W_lin_in = (const float*)d_in[9];
  const float* b_lin_in = (const float*)d_in[10];
  const float* W_mlp    = (const float*)d_in[11];
  const float* b_mlp    = (const float*)d_in[12];
  const float* W_out    = (const float*)d_in[13];
  const float* b_out    = (const float*)d_in[14];
  float* out = (float*)d_out;

  char* ws = (char*)d_ws;
  int*   flag     = (int*)(ws + WS_FLAG);
  int*   sel      = (int*)(ws + WS_SEL);
  int*   vint     = (int*)(ws + WS_VINT);
  int*   vbyte    = (int*)(ws + WS_VBYTE);
  float* partial  = (float*)(ws + WS_PART);
  float* rep_bias = (float*)(ws + WS_REPB);

  k_valid<<<NROW / 4, 256, 0, stream>>>(mask, vint, vbyte);
  k_select<<<BB, 64, 0, stream>>>(mask, vint, vbyte, sample_size, flag, sel);
  k_image<<<512, 256, 0, stream>>>(Imodel, Iobs, metadata, mask, flag, sel,
                                   sample_size, W_img_in, b_img_in, W_img,
                                   b_img, partial);
  k_rep<<<BB, 32, 0, stream>>>(partial, b_lin_in, rep_bias);
  k_scale<<<1536, 256, 0, stream>>>(metadata, mask, flag, W_lin_in, rep_bias,
                                    W_mlp, b_mlp, W_out, b_out, out);
}